// Round 12
// baseline (36.336 us; speedup 1.0000x reference)
//
#include <hip/hip_runtime.h>

#define N_NEUR 4096
#define T_STEPS 2048
#define DT 0.001f
#define TAU 10.0f
#define V_TH 100.0f
#define V_R -100.0f
#define DECAY (1.0f - DT / TAU)   // 0.9999f

#define SEG 16                    // time steps per prefix sub-segment
#define NSEG (T_STEPS / SEG)      // 128 sub-segments
#define BETA (DT * (float)SEG)    // 0.016 — per-segment bootstrap constant
#define NF4 (N_NEUR / 4)          // 1024 float4 columns
#define PRE_B (NSEG * 4)          // 512 blocks

typedef float f4 __attribute__((ext_vector_type(4)));

// ---------------------------------------------------------------------------
// Spike-impossibility proof (segment-wise bootstrap, per neuron):
// While no spike has occurred anywhere, exactly:
//   u_t = u0 + DT*S_t + DT*sum_{j<t} u_j^2 + (decay-sum of s0, |.| <= TAU|s0|)
// Per sub-segment g (16 steps), with base = S at segment start and P_g =
// max in-segment |S_t - base|:  K_g = |u0| + TAU|s0| + eps + DT*(|base|+P_g) + c_g,
// M_g = 1.5*K_g. If (checked in fp) M_g >= K_g + BETA*M_g^2 then |u_t| <= M_g
// throughout segment g by induction; c_{g+1} = c_g + BETA*M_g^2. If also
// M_g < 50 (half of v_th, ~100x above actual dynamics) for all g,i -> no spike
// can ever fire -> s is pure decay -> out[t] = s0*DECAY^(t+1).
// Any failed / NaN check falls to the exact sequential simulator.
// ---------------------------------------------------------------------------

// K1 (512 blocks x 256): fused out-writer + x-prefix-stats (R10 k_pre, best
// measured) + ctl-word init by block 0 (visible to K2 via kernel boundary).
__global__ __launch_bounds__(256, 2) void k_main(const float* __restrict__ x,
                                                 const float* __restrict__ s0,
                                                 float* __restrict__ out,
                                                 float* __restrict__ seg,
                                                 int* __restrict__ ctl) {
    const int b = (int)blockIdx.x;
    const int tid = (int)threadIdx.x;
    if (b == 0 && tid == 0) { ctl[0] = 0; ctl[1] = 0; }   // arrive-counter, verdict

    const int ss = b >> 2;
    const int st = b & 3;
    const int f4c = st * 256 + tid;
    const int row0 = ss * SEG;

    // s0 first (oldest outstanding load)
    const f4 sv = ((const f4*)s0)[f4c];

    // issue all 16 x loads (streaming, read-once)
    const f4* xp = (const f4*)x + (size_t)row0 * NF4 + f4c;
    f4 L[SEG];
    #pragma unroll
    for (int k = 0; k < SEG; ++k)
        L[k] = __builtin_nontemporal_load(&xp[(size_t)k * NF4]);

    // out tile: needs only sv -> stores issue under x-load latency
    float scale = powf(DECAY, (float)(row0 + 1));
    f4* op = (f4*)out + (size_t)row0 * NF4 + f4c;
    #pragma unroll
    for (int k = 0; k < SEG; ++k) {
        f4 v = sv * scale;
        __builtin_nontemporal_store(v, &op[(size_t)k * NF4]);
        scale *= DECAY;
    }

    // prefix chains over the 16 rows
    f4 run = {0.f, 0.f, 0.f, 0.f};
    f4 mx  = {0.f, 0.f, 0.f, 0.f};
    f4 mn  = {0.f, 0.f, 0.f, 0.f};
    #pragma unroll
    for (int k = 0; k < SEG; ++k) {
        run.x += L[k].x; mx.x = fmaxf(mx.x, run.x); mn.x = fminf(mn.x, run.x);
        run.y += L[k].y; mx.y = fmaxf(mx.y, run.y); mn.y = fminf(mn.y, run.y);
        run.z += L[k].z; mx.z = fmaxf(mx.z, run.z); mn.z = fminf(mn.z, run.z);
        run.w += L[k].w; mx.w = fmaxf(mx.w, run.w); mn.w = fminf(mn.w, run.w);
    }
    // packed per-neuron float2 {sum, P}: seg2[g*N + i]; normal stores (L2-warm
    // for K2's re-read)
    const f4 a = {run.x, fmaxf(mx.x, -mn.x), run.y, fmaxf(mx.y, -mn.y)};
    const f4 c = {run.z, fmaxf(mx.z, -mn.z), run.w, fmaxf(mx.w, -mn.w)};
    f4* sp = (f4*)seg + (size_t)ss * (N_NEUR / 2) + (size_t)f4c * 2;
    sp[0] = a;
    sp[1] = c;
}

// K2 (4 blocks x 1024): bootstrap combine + last-block exact-sim fallback.
// Each thread owns one neuron. Blocks OR their verdict into ctl[1], then
// count arrival in ctl[0]; the LAST block acquires and (iff bad) runs the
// exact sequential simulation with its 1024 threads.
#define CSEG 32
__global__ __launch_bounds__(1024) void k_finish(const float* __restrict__ x,
                                                 const float* __restrict__ W,
                                                 const float* __restrict__ u0,
                                                 const float* __restrict__ s0,
                                                 const float* __restrict__ seg,
                                                 float* __restrict__ out,
                                                 int* __restrict__ ctl) {
    const int tid = (int)threadIdx.x;
    const int i = (int)blockIdx.x * 1024 + tid;

    // ---- per-neuron segment-wise bootstrap ----
    const float base_term = fabsf(u0[i]) + TAU * fabsf(s0[i]) + 1e-3f;
    const float2* seg2 = (const float2*)seg;

    bool bad = false;
    float base = 0.f;     // running prefix sum at segment start
    float cq = 0.f;       // accumulated quadratic bound DT*sum u^2
    #pragma unroll 1
    for (int c0 = 0; c0 < NSEG; c0 += CSEG) {
        float2 SP[CSEG];
        #pragma unroll
        for (int k = 0; k < CSEG; ++k)
            SP[k] = seg2[(size_t)(c0 + k) * N_NEUR + i];
        #pragma unroll
        for (int k = 0; k < CSEG; ++k) {
            const float K = base_term + DT * (fabsf(base) + SP[k].y) + cq;
            const float M = 1.5f * K;
            bad |= !(M >= K + BETA * M * M);       // bootstrap check (NaN-safe)
            bad |= !(M < 50.0f);                   // spike margin check
            cq += BETA * M * M;
            base += SP[k].x;
        }
    }

    // ---- block verdict ----
    __shared__ int blkbad;
    __shared__ int lastflag;
    __shared__ int globad;
    if (tid == 0) { blkbad = 0; lastflag = 0; globad = 0; }
    __syncthreads();
    if (bad) atomicOr(&blkbad, 1);
    __syncthreads();

    if (tid == 0) {
        if (blkbad) atomicOr(&ctl[1], 1);          // device-scope verdict OR
        __threadfence();                           // release
        const int old = atomicAdd(&ctl[0], 1);     // arrive
        if (old == 3) {                            // last of 4 blocks
            lastflag = 1;
            __threadfence();                       // acquire
            globad = atomicOr(&ctl[1], 0);         // coherent read
        }
    }
    __syncthreads();
    if (!lastflag || globad == 0) return;          // expected path: fast exit

    // ---- exact sequential fallback (last block only; never for in-dist data)
    __shared__ float u[N_NEUR];
    __shared__ float s[N_NEUR];
    __shared__ int list[N_NEUR];
    __shared__ int cnt;
    for (int m = tid; m < N_NEUR; m += 1024) { u[m] = u0[m]; s[m] = s0[m]; }
    if (tid == 0) cnt = 0;
    __syncthreads();
    for (int t = 0; t < T_STEPS; ++t) {
        #pragma unroll
        for (int q = 0; q < 4; ++q) {
            const int ii = tid + q * 1024;
            const float ui = u[ii];
            const bool spk = ui >= V_TH;
            float un = ui + DT * (ui * ui + x[(size_t)t * N_NEUR + ii] + s[ii]);
            if (spk) {
                int p = atomicAdd(&cnt, 1);
                list[p] = ii;
                un = V_R;
            }
            u[ii] = un;
        }
        __syncthreads();
        const int k = cnt;
        #pragma unroll
        for (int q = 0; q < 4; ++q) {
            const int ii = tid + q * 1024;
            float acc = 0.f;
            for (int m = 0; m < k; ++m) acc += W[(size_t)ii * N_NEUR + list[m]];
            const float sn = s[ii] * DECAY + acc;
            s[ii] = sn;
            out[(size_t)t * N_NEUR + ii] = sn;
        }
        __syncthreads();
        if (tid == 0) cnt = 0;
        __syncthreads();
    }
}

// ---------------------------------------------------------------------------
// Fallback path (round-3 proven) if ws is too small for seg arrays.
// ---------------------------------------------------------------------------
#define NSCAN 64
#define CH 64
#define NCH (T_STEPS / CH)

__global__ __launch_bounds__(64, 1) void k_scan_fb(const float* __restrict__ x,
                                                   const float* __restrict__ u0,
                                                   const float* __restrict__ s0,
                                                   float* __restrict__ out,
                                                   int* __restrict__ flags) {
    const int b = (int)blockIdx.x;
    const int tid = (int)threadIdx.x;
    if (b >= NSCAN) {
        const int t = b - NSCAN;
        const float scale = powf(DECAY, (float)(t + 1));
        const float4* s4 = (const float4*)s0;
        float4* o4 = (float4*)out + (size_t)t * NF4;
        #pragma unroll
        for (int p = 0; p < 16; ++p) {
            const int c = p * 64 + tid;
            float4 v = s4[c];
            v.x *= scale; v.y *= scale; v.z *= scale; v.w *= scale;
            o4[c] = v;
        }
        return;
    }
    const int i = b * 64 + tid;
    const float* xp = x + i;
    float uu = u0[i], ss = s0[i], um = uu;
    float A[CH], B[CH], C[CH];
    auto loadch = [&](float (&dst)[CH], int ck) {
        const float* p = xp + (size_t)ck * CH * N_NEUR;
        #pragma unroll
        for (int k = 0; k < CH; ++k) dst[k] = p[(size_t)k * N_NEUR];
    };
    auto compch = [&](const float (&src)[CH]) {
        #pragma unroll
        for (int k = 0; k < CH; ++k) {
            um = fmaxf(um, uu);
            uu = fmaf(DT, fmaf(uu, uu, src[k] + ss), uu);
            ss *= DECAY;
        }
    };
    loadch(A, 0); loadch(B, 1);
    #pragma unroll 1
    for (int c = 0; c < NCH - 2; c += 3) {
        loadch(C, c + 2); compch(A);
        loadch(A, c + 3); compch(B);
        loadch(B, c + 4); compch(C);
    }
    compch(A); compch(B);
    const unsigned long long anyb = __ballot(um >= 50.0f);
    if (tid == 0) flags[b] = (anyb != 0ull) ? 1 : 0;
}

__global__ __launch_bounds__(1024) void k_slow_fb(const float* __restrict__ x,
                                                  const float* __restrict__ W,
                                                  const float* __restrict__ u0,
                                                  const float* __restrict__ s0,
                                                  float* __restrict__ out,
                                                  const int* __restrict__ flags) {
    __shared__ int any;
    const int tid = (int)threadIdx.x;
    if (tid == 0) any = 0;
    __syncthreads();
    if (tid < NSCAN && flags[tid] != 0) any = 1;
    __syncthreads();
    if (any == 0) return;
    __shared__ float u[N_NEUR];
    __shared__ float s[N_NEUR];
    __shared__ int list[N_NEUR];
    __shared__ int cnt;
    for (int m = tid; m < N_NEUR; m += 1024) { u[m] = u0[m]; s[m] = s0[m]; }
    if (tid == 0) cnt = 0;
    __syncthreads();
    for (int t = 0; t < T_STEPS; ++t) {
        #pragma unroll
        for (int q = 0; q < 4; ++q) {
            const int i = tid + q * 1024;
            const float ui = u[i];
            const bool spk = ui >= V_TH;
            float un = ui + DT * (ui * ui + x[(size_t)t * N_NEUR + i] + s[i]);
            if (spk) { int p = atomicAdd(&cnt, 1); list[p] = i; un = V_R; }
            u[i] = un;
        }
        __syncthreads();
        const int k = cnt;
        #pragma unroll
        for (int q = 0; q < 4; ++q) {
            const int i = tid + q * 1024;
            float acc = 0.f;
            for (int m = 0; m < k; ++m) acc += W[(size_t)i * N_NEUR + list[m]];
            const float sn = s[i] * DECAY + acc;
            s[i] = sn;
            out[(size_t)t * N_NEUR + i] = sn;
        }
        __syncthreads();
        if (tid == 0) cnt = 0;
        __syncthreads();
    }
}

// ---------------------------------------------------------------------------
extern "C" void kernel_launch(void* const* d_in, const int* in_sizes, int n_in,
                              void* d_out, int out_size, void* d_ws, size_t ws_size,
                              hipStream_t stream) {
    const float* x  = (const float*)d_in[0];   // [T, N]
    const float* W  = (const float*)d_in[1];   // [N, N]
    const float* u0 = (const float*)d_in[2];   // [N]
    const float* s0 = (const float*)d_in[3];   // [N]
    float* out = (float*)d_out;                // [T, N]

    const size_t seg_elems = (size_t)NSEG * N_NEUR * 2;    // 1M floats (4 MB)
    if (ws_size >= seg_elems * sizeof(float) + 2 * sizeof(int)) {
        float* seg = (float*)d_ws;
        int* ctl   = (int*)(seg + seg_elems);              // [0]=arrive, [1]=verdict
        k_main<<<PRE_B, 256, 0, stream>>>(x, s0, out, seg, ctl);
        k_finish<<<4, 1024, 0, stream>>>(x, W, u0, s0, seg, out, ctl);
    } else {
        int* flags = (int*)d_ws;
        k_scan_fb<<<NSCAN + T_STEPS, 64, 0, stream>>>(x, u0, s0, out, flags);
        k_slow_fb<<<1, 1024, 0, stream>>>(x, W, u0, s0, out, flags);
    }
}

// Round 13
// 25.915 us; speedup vs baseline: 1.4021x; 1.4021x over previous
//
#include <hip/hip_runtime.h>

#define N_NEUR 4096
#define T_STEPS 2048
#define DT 0.001f
#define TAU 10.0f
#define V_TH 100.0f
#define V_R -100.0f
#define DECAY (1.0f - DT / TAU)   // 0.9999f

#define SEG 16                    // time steps per prefix sub-segment
#define NSEG (T_STEPS / SEG)      // 128 sub-segments
#define BETA (DT * (float)SEG)    // 0.016 — per-segment bootstrap constant
#define NF4 (N_NEUR / 4)          // 1024 float4 columns
#define PRE_B (NSEG * 4)          // 512 blocks

typedef float f4 __attribute__((ext_vector_type(4)));

// ---------------------------------------------------------------------------
// Spike-impossibility proof (segment-wise bootstrap, per neuron):
// While no spike has occurred anywhere, exactly:
//   u_t = u0 + DT*S_t + DT*sum_{j<t} u_j^2 + (decay-sum of s0, |.| <= TAU|s0|)
// Per sub-segment g (16 steps), with base = S at segment start and P_g =
// max in-segment |S_t - base|:  K_g = |u0| + TAU|s0| + eps + DT*(|base|+P_g) + c_g,
// M_g = 1.5*K_g. If (checked in fp) M_g >= K_g + BETA*M_g^2 then |u_t| <= M_g
// throughout segment g by induction; c_{g+1} = c_g + BETA*M_g^2. If also
// M_g < 50 (half of v_th, ~100x above actual dynamics) for all g,i -> no spike
// can ever fire -> s is pure decay -> out[t] = s0*DECAY^(t+1).
// Any failed / NaN check falls to the exact sequential simulator.
// ---------------------------------------------------------------------------

// K1 (512 blocks x 256): fused out-writer + x-prefix-stats (R10 k_pre,
// measured best) + ctl-word init by block 0 (visible to K2 via kernel
// boundary; K1's other blocks never touch ctl).
__global__ __launch_bounds__(256, 2) void k_main(const float* __restrict__ x,
                                                 const float* __restrict__ s0,
                                                 float* __restrict__ out,
                                                 float* __restrict__ seg,
                                                 int* __restrict__ ctl) {
    const int b = (int)blockIdx.x;
    const int tid = (int)threadIdx.x;
    if (b == 0 && tid == 0) { ctl[0] = 0; ctl[1] = 0; }   // arrive-counter, verdict

    const int ss = b >> 2;
    const int st = b & 3;
    const int f4c = st * 256 + tid;
    const int row0 = ss * SEG;

    // s0 first (oldest outstanding load)
    const f4 sv = ((const f4*)s0)[f4c];

    // issue all 16 x loads (streaming, read-once)
    const f4* xp = (const f4*)x + (size_t)row0 * NF4 + f4c;
    f4 L[SEG];
    #pragma unroll
    for (int k = 0; k < SEG; ++k)
        L[k] = __builtin_nontemporal_load(&xp[(size_t)k * NF4]);

    // out tile: needs only sv -> stores issue under x-load latency
    float scale = powf(DECAY, (float)(row0 + 1));
    f4* op = (f4*)out + (size_t)row0 * NF4 + f4c;
    #pragma unroll
    for (int k = 0; k < SEG; ++k) {
        f4 v = sv * scale;
        __builtin_nontemporal_store(v, &op[(size_t)k * NF4]);
        scale *= DECAY;
    }

    // prefix chains over the 16 rows
    f4 run = {0.f, 0.f, 0.f, 0.f};
    f4 mx  = {0.f, 0.f, 0.f, 0.f};
    f4 mn  = {0.f, 0.f, 0.f, 0.f};
    #pragma unroll
    for (int k = 0; k < SEG; ++k) {
        run.x += L[k].x; mx.x = fmaxf(mx.x, run.x); mn.x = fminf(mn.x, run.x);
        run.y += L[k].y; mx.y = fmaxf(mx.y, run.y); mn.y = fminf(mn.y, run.y);
        run.z += L[k].z; mx.z = fmaxf(mx.z, run.z); mn.z = fminf(mn.z, run.z);
        run.w += L[k].w; mx.w = fmaxf(mx.w, run.w); mn.w = fminf(mn.w, run.w);
    }
    // packed per-neuron float2 {sum, P}: seg2[g*N + i]; normal stores (stay
    // L2-warm for K2's re-read)
    const f4 a = {run.x, fmaxf(mx.x, -mn.x), run.y, fmaxf(mx.y, -mn.y)};
    const f4 c = {run.z, fmaxf(mx.z, -mn.z), run.w, fmaxf(mx.w, -mn.w)};
    f4* sp = (f4*)seg + (size_t)ss * (N_NEUR / 2) + (size_t)f4c * 2;
    sp[0] = a;
    sp[1] = c;
}

// K2 (32 blocks x 128): bootstrap combine (R10 geometry, proven ~2.3 us) +
// last-arriving-block exact-sim fallback (merged k_slow: saves one node).
#define CSEG 32
__global__ __launch_bounds__(128) void k_finish(const float* __restrict__ x,
                                                const float* __restrict__ W,
                                                const float* __restrict__ u0,
                                                const float* __restrict__ s0,
                                                const float* __restrict__ seg,
                                                float* __restrict__ out,
                                                int* __restrict__ ctl) {
    const int tid = (int)threadIdx.x;
    const int i = (int)blockIdx.x * 128 + tid;

    // ---- per-neuron segment-wise bootstrap ----
    const float base_term = fabsf(u0[i]) + TAU * fabsf(s0[i]) + 1e-3f;
    const float2* seg2 = (const float2*)seg;

    bool bad = false;
    float base = 0.f;     // running prefix sum at segment start
    float cq = 0.f;       // accumulated quadratic bound DT*sum u^2
    #pragma unroll 1
    for (int c0 = 0; c0 < NSEG; c0 += CSEG) {
        float2 SP[CSEG];
        #pragma unroll
        for (int k = 0; k < CSEG; ++k)
            SP[k] = seg2[(size_t)(c0 + k) * N_NEUR + i];
        #pragma unroll
        for (int k = 0; k < CSEG; ++k) {
            const float K = base_term + DT * (fabsf(base) + SP[k].y) + cq;
            const float M = 1.5f * K;
            bad |= !(M >= K + BETA * M * M);       // bootstrap check (NaN-safe)
            bad |= !(M < 50.0f);                   // spike margin check
            cq += BETA * M * M;
            base += SP[k].x;
        }
    }

    // ---- verdict + arrival protocol ----
    __shared__ int blkbad;
    __shared__ int lastflag;
    __shared__ int globad;
    if (tid == 0) { blkbad = 0; lastflag = 0; globad = 0; }
    __syncthreads();
    if (bad) atomicOr(&blkbad, 1);
    __syncthreads();
    if (tid == 0) {
        if (blkbad) atomicOr(&ctl[1], 1);          // device-scope verdict OR
        __threadfence();                           // release before arrive
        const int old = atomicAdd(&ctl[0], 1);     // arrive
        if (old == 31) {                           // last of 32 blocks
            lastflag = 1;
            __threadfence();                       // acquire
            globad = atomicOr(&ctl[1], 0);         // coherent read
        }
    }
    __syncthreads();
    if (!lastflag || globad == 0) return;          // expected path: fast exit

    // ---- exact sequential fallback (last block only, 128 threads;
    //      correctness-only path, never taken for in-distribution data) ----
    __shared__ float u[N_NEUR];
    __shared__ float s[N_NEUR];
    __shared__ int list[N_NEUR];
    __shared__ int cnt;
    for (int m = tid; m < N_NEUR; m += 128) { u[m] = u0[m]; s[m] = s0[m]; }
    if (tid == 0) cnt = 0;
    __syncthreads();
    for (int t = 0; t < T_STEPS; ++t) {
        #pragma unroll
        for (int q = 0; q < 32; ++q) {
            const int ii = tid + q * 128;
            const float ui = u[ii];
            const bool spk = ui >= V_TH;
            float un = ui + DT * (ui * ui + x[(size_t)t * N_NEUR + ii] + s[ii]);
            if (spk) {
                int p = atomicAdd(&cnt, 1);
                list[p] = ii;
                un = V_R;
            }
            u[ii] = un;
        }
        __syncthreads();
        const int k = cnt;
        #pragma unroll
        for (int q = 0; q < 32; ++q) {
            const int ii = tid + q * 128;
            float acc = 0.f;
            for (int m = 0; m < k; ++m) acc += W[(size_t)ii * N_NEUR + list[m]];
            const float sn = s[ii] * DECAY + acc;
            s[ii] = sn;
            out[(size_t)t * N_NEUR + ii] = sn;
        }
        __syncthreads();
        if (tid == 0) cnt = 0;
        __syncthreads();
    }
}

// ---------------------------------------------------------------------------
// Fallback path (round-3 proven) if ws is too small for seg arrays.
// ---------------------------------------------------------------------------
#define NSCAN 64
#define CH 64
#define NCH (T_STEPS / CH)

__global__ __launch_bounds__(64, 1) void k_scan_fb(const float* __restrict__ x,
                                                   const float* __restrict__ u0,
                                                   const float* __restrict__ s0,
                                                   float* __restrict__ out,
                                                   int* __restrict__ flags) {
    const int b = (int)blockIdx.x;
    const int tid = (int)threadIdx.x;
    if (b >= NSCAN) {
        const int t = b - NSCAN;
        const float scale = powf(DECAY, (float)(t + 1));
        const float4* s4 = (const float4*)s0;
        float4* o4 = (float4*)out + (size_t)t * NF4;
        #pragma unroll
        for (int p = 0; p < 16; ++p) {
            const int c = p * 64 + tid;
            float4 v = s4[c];
            v.x *= scale; v.y *= scale; v.z *= scale; v.w *= scale;
            o4[c] = v;
        }
        return;
    }
    const int i = b * 64 + tid;
    const float* xp = x + i;
    float uu = u0[i], ss = s0[i], um = uu;
    float A[CH], B[CH], C[CH];
    auto loadch = [&](float (&dst)[CH], int ck) {
        const float* p = xp + (size_t)ck * CH * N_NEUR;
        #pragma unroll
        for (int k = 0; k < CH; ++k) dst[k] = p[(size_t)k * N_NEUR];
    };
    auto compch = [&](const float (&src)[CH]) {
        #pragma unroll
        for (int k = 0; k < CH; ++k) {
            um = fmaxf(um, uu);
            uu = fmaf(DT, fmaf(uu, uu, src[k] + ss), uu);
            ss *= DECAY;
        }
    };
    loadch(A, 0); loadch(B, 1);
    #pragma unroll 1
    for (int c = 0; c < NCH - 2; c += 3) {
        loadch(C, c + 2); compch(A);
        loadch(A, c + 3); compch(B);
        loadch(B, c + 4); compch(C);
    }
    compch(A); compch(B);
    const unsigned long long anyb = __ballot(um >= 50.0f);
    if (tid == 0) flags[b] = (anyb != 0ull) ? 1 : 0;
}

__global__ __launch_bounds__(1024) void k_slow_fb(const float* __restrict__ x,
                                                  const float* __restrict__ W,
                                                  const float* __restrict__ u0,
                                                  const float* __restrict__ s0,
                                                  float* __restrict__ out,
                                                  const int* __restrict__ flags) {
    __shared__ int any;
    const int tid = (int)threadIdx.x;
    if (tid == 0) any = 0;
    __syncthreads();
    if (tid < NSCAN && flags[tid] != 0) any = 1;
    __syncthreads();
    if (any == 0) return;
    __shared__ float u[N_NEUR];
    __shared__ float s[N_NEUR];
    __shared__ int list[N_NEUR];
    __shared__ int cnt;
    for (int m = tid; m < N_NEUR; m += 1024) { u[m] = u0[m]; s[m] = s0[m]; }
    if (tid == 0) cnt = 0;
    __syncthreads();
    for (int t = 0; t < T_STEPS; ++t) {
        #pragma unroll
        for (int q = 0; q < 4; ++q) {
            const int i = tid + q * 1024;
            const float ui = u[i];
            const bool spk = ui >= V_TH;
            float un = ui + DT * (ui * ui + x[(size_t)t * N_NEUR + i] + s[i]);
            if (spk) { int p = atomicAdd(&cnt, 1); list[p] = i; un = V_R; }
            u[i] = un;
        }
        __syncthreads();
        const int k = cnt;
        #pragma unroll
        for (int q = 0; q < 4; ++q) {
            const int i = tid + q * 1024;
            float acc = 0.f;
            for (int m = 0; m < k; ++m) acc += W[(size_t)i * N_NEUR + list[m]];
            const float sn = s[i] * DECAY + acc;
            s[i] = sn;
            out[(size_t)t * N_NEUR + i] = sn;
        }
        __syncthreads();
        if (tid == 0) cnt = 0;
        __syncthreads();
    }
}

// ---------------------------------------------------------------------------
extern "C" void kernel_launch(void* const* d_in, const int* in_sizes, int n_in,
                              void* d_out, int out_size, void* d_ws, size_t ws_size,
                              hipStream_t stream) {
    const float* x  = (const float*)d_in[0];   // [T, N]
    const float* W  = (const float*)d_in[1];   // [N, N]
    const float* u0 = (const float*)d_in[2];   // [N]
    const float* s0 = (const float*)d_in[3];   // [N]
    float* out = (float*)d_out;                // [T, N]

    const size_t seg_elems = (size_t)NSEG * N_NEUR * 2;    // 1M floats (4 MB)
    if (ws_size >= seg_elems * sizeof(float) + 2 * sizeof(int)) {
        float* seg = (float*)d_ws;
        int* ctl   = (int*)(seg + seg_elems);              // [0]=arrive, [1]=verdict
        k_main<<<PRE_B, 256, 0, stream>>>(x, s0, out, seg, ctl);
        k_finish<<<32, 128, 0, stream>>>(x, W, u0, s0, seg, out, ctl);
    } else {
        int* flags = (int*)d_ws;
        k_scan_fb<<<NSCAN + T_STEPS, 64, 0, stream>>>(x, u0, s0, out, flags);
        k_slow_fb<<<1, 1024, 0, stream>>>(x, W, u0, s0, out, flags);
    }
}

// Round 14
// 25.085 us; speedup vs baseline: 1.4485x; 1.0331x over previous
//
#include <hip/hip_runtime.h>

#define N_NEUR 4096
#define T_STEPS 2048
#define DT 0.001f
#define TAU 10.0f
#define V_TH 100.0f
#define V_R -100.0f
#define DECAY (1.0f - DT / TAU)   // 0.9999f

#define SEG 16                    // time steps per prefix sub-segment
#define NSEG (T_STEPS / SEG)      // 128 sub-segments
#define BETA (DT * (float)SEG)    // 0.016 — per-segment bootstrap constant
#define NF4 (N_NEUR / 4)          // 1024 float4 columns
#define STRIPE 16                 // 16 stripes of 64 float4 cols
#define PRE_B (NSEG * STRIPE)     // 2048 blocks

typedef float f4 __attribute__((ext_vector_type(4)));

// ---------------------------------------------------------------------------
// Spike-impossibility proof (segment-wise bootstrap, per neuron):
// While no spike has occurred anywhere, exactly:
//   u_t = u0 + DT*S_t + DT*sum_{j<t} u_j^2 + (decay-sum of s0, |.| <= TAU|s0|)
// Per sub-segment g (16 steps), with base = S at segment start and P_g =
// max in-segment |S_t - base|:  K_g = |u0| + TAU|s0| + eps + DT*(|base|+P_g) + c_g,
// M_g = 1.5*K_g. If (checked in fp) M_g >= K_g + BETA*M_g^2 then |u_t| <= M_g
// throughout segment g by induction; c_{g+1} = c_g + BETA*M_g^2. If also
// M_g < 50 (half of v_th, ~100x above actual dynamics) for all g,i -> no spike
// can ever fire -> s is pure decay -> out[t] = s0*DECAY^(t+1).
// Any failed / NaN check falls to the exact sequential simulator.
// ---------------------------------------------------------------------------

// K1 (2048 blocks x 256, 32 waves/CU): fused out-writer + x-prefix-stats.
// Block b: subseg ss=b>>4 (16 rows), stripe st=b&15 (64 float4 cols).
// Thread: column c=tid&63, quarter q=tid>>6 (rows q*4..q*4+3).
// Prefix stats COMPOSE across quarters: mx_tot = max_q(base_q + mx_q),
// base_q = sum of prior quarters — combined in LDS by the q==0 wave.
// 4x the wave-occupancy of the R10/R13 k_pre (latency-bound fix).
__global__ __launch_bounds__(256, 8) void k_main(const float* __restrict__ x,
                                                 const float* __restrict__ s0,
                                                 float* __restrict__ out,
                                                 float* __restrict__ seg,
                                                 int* __restrict__ ctl) {
    const int b = (int)blockIdx.x;
    const int tid = (int)threadIdx.x;
    if (b == 0 && tid == 0) { ctl[0] = 0; ctl[1] = 0; }   // arrive-counter, verdict

    const int ss = b >> 4;
    const int st = b & 15;
    const int c  = tid & 63;
    const int q  = tid >> 6;
    const int f4c = st * 64 + c;
    const int row0 = ss * SEG + q * 4;

    // s0 (L2-cached after first touch; 4x redundant read is cheap)
    const f4 sv = ((const f4*)s0)[f4c];

    // 4 x-loads, streaming
    const f4* xp = (const f4*)x + (size_t)row0 * NF4 + f4c;
    f4 L[4];
    #pragma unroll
    for (int k = 0; k < 4; ++k)
        L[k] = __builtin_nontemporal_load(&xp[(size_t)k * NF4]);

    // out rows row0..row0+3 (need only sv -> issue under x-load latency)
    float scale = powf(DECAY, (float)(row0 + 1));
    f4* op = (f4*)out + (size_t)row0 * NF4 + f4c;
    #pragma unroll
    for (int k = 0; k < 4; ++k) {
        f4 v = sv * scale;
        __builtin_nontemporal_store(v, &op[(size_t)k * NF4]);
        scale *= DECAY;
    }

    // partial prefix over 4 rows
    f4 run = {0.f, 0.f, 0.f, 0.f};
    f4 mx  = {0.f, 0.f, 0.f, 0.f};
    f4 mn  = {0.f, 0.f, 0.f, 0.f};
    #pragma unroll
    for (int k = 0; k < 4; ++k) {
        run.x += L[k].x; mx.x = fmaxf(mx.x, run.x); mn.x = fminf(mn.x, run.x);
        run.y += L[k].y; mx.y = fmaxf(mx.y, run.y); mn.y = fminf(mn.y, run.y);
        run.z += L[k].z; mx.z = fmaxf(mx.z, run.z); mn.z = fminf(mn.z, run.z);
        run.w += L[k].w; mx.w = fmaxf(mx.w, run.w); mn.w = fminf(mn.w, run.w);
    }

    // combine quarters in LDS (12 KB/block; 8 blocks/CU = 96 KB < 160)
    __shared__ f4 Lsum[4][64];
    __shared__ f4 Lmx[4][64];
    __shared__ f4 Lmn[4][64];
    Lsum[q][c] = run;
    Lmx[q][c]  = mx;
    Lmn[q][c]  = mn;
    __syncthreads();

    if (q == 0) {
        float bx = 0.f, by = 0.f, bz = 0.f, bw = 0.f;
        float Mx = 0.f, My = 0.f, Mz = 0.f, Mw = 0.f;
        float Nx = 0.f, Ny = 0.f, Nz = 0.f, Nw = 0.f;
        #pragma unroll
        for (int qq = 0; qq < 4; ++qq) {
            const f4 sS = Lsum[qq][c];
            const f4 sM = Lmx[qq][c];
            const f4 sN = Lmn[qq][c];
            Mx = fmaxf(Mx, bx + sM.x); Nx = fminf(Nx, bx + sN.x); bx += sS.x;
            My = fmaxf(My, by + sM.y); Ny = fminf(Ny, by + sN.y); by += sS.y;
            Mz = fmaxf(Mz, bz + sM.z); Nz = fminf(Nz, bz + sN.z); bz += sS.z;
            Mw = fmaxf(Mw, bw + sM.w); Nw = fminf(Nw, bw + sN.w); bw += sS.w;
        }
        // packed per-neuron float2 {sum, P}: seg2[g*N + i] (same layout as R13)
        const f4 a  = {bx, fmaxf(Mx, -Nx), by, fmaxf(My, -Ny)};
        const f4 cc = {bz, fmaxf(Mz, -Nz), bw, fmaxf(Mw, -Nw)};
        f4* sp = (f4*)seg + (size_t)ss * (N_NEUR / 2) + (size_t)f4c * 2;
        sp[0] = a;
        sp[1] = cc;
    }
}

// K2 (32 blocks x 128): bootstrap combine + last-arriving-block exact-sim
// fallback (R13, proven).
#define CSEG 32
__global__ __launch_bounds__(128) void k_finish(const float* __restrict__ x,
                                                const float* __restrict__ W,
                                                const float* __restrict__ u0,
                                                const float* __restrict__ s0,
                                                const float* __restrict__ seg,
                                                float* __restrict__ out,
                                                int* __restrict__ ctl) {
    const int tid = (int)threadIdx.x;
    const int i = (int)blockIdx.x * 128 + tid;

    const float base_term = fabsf(u0[i]) + TAU * fabsf(s0[i]) + 1e-3f;
    const float2* seg2 = (const float2*)seg;

    bool bad = false;
    float base = 0.f;
    float cq = 0.f;
    #pragma unroll 1
    for (int c0 = 0; c0 < NSEG; c0 += CSEG) {
        float2 SP[CSEG];
        #pragma unroll
        for (int k = 0; k < CSEG; ++k)
            SP[k] = seg2[(size_t)(c0 + k) * N_NEUR + i];
        #pragma unroll
        for (int k = 0; k < CSEG; ++k) {
            const float K = base_term + DT * (fabsf(base) + SP[k].y) + cq;
            const float M = 1.5f * K;
            bad |= !(M >= K + BETA * M * M);       // bootstrap check (NaN-safe)
            bad |= !(M < 50.0f);                   // spike margin check
            cq += BETA * M * M;
            base += SP[k].x;
        }
    }

    __shared__ int blkbad;
    __shared__ int lastflag;
    __shared__ int globad;
    if (tid == 0) { blkbad = 0; lastflag = 0; globad = 0; }
    __syncthreads();
    if (bad) atomicOr(&blkbad, 1);
    __syncthreads();
    if (tid == 0) {
        if (blkbad) atomicOr(&ctl[1], 1);          // device-scope verdict OR
        __threadfence();                           // release before arrive
        const int old = atomicAdd(&ctl[0], 1);     // arrive
        if (old == 31) {                           // last of 32 blocks
            lastflag = 1;
            __threadfence();                       // acquire
            globad = atomicOr(&ctl[1], 0);         // coherent read
        }
    }
    __syncthreads();
    if (!lastflag || globad == 0) return;          // expected path: fast exit

    // exact sequential fallback (last block only; never for in-dist data)
    __shared__ float u[N_NEUR];
    __shared__ float s[N_NEUR];
    __shared__ int list[N_NEUR];
    __shared__ int cnt;
    for (int m = tid; m < N_NEUR; m += 128) { u[m] = u0[m]; s[m] = s0[m]; }
    if (tid == 0) cnt = 0;
    __syncthreads();
    for (int t = 0; t < T_STEPS; ++t) {
        #pragma unroll
        for (int qq = 0; qq < 32; ++qq) {
            const int ii = tid + qq * 128;
            const float ui = u[ii];
            const bool spk = ui >= V_TH;
            float un = ui + DT * (ui * ui + x[(size_t)t * N_NEUR + ii] + s[ii]);
            if (spk) {
                int p = atomicAdd(&cnt, 1);
                list[p] = ii;
                un = V_R;
            }
            u[ii] = un;
        }
        __syncthreads();
        const int k = cnt;
        #pragma unroll
        for (int qq = 0; qq < 32; ++qq) {
            const int ii = tid + qq * 128;
            float acc = 0.f;
            for (int m = 0; m < k; ++m) acc += W[(size_t)ii * N_NEUR + list[m]];
            const float sn = s[ii] * DECAY + acc;
            s[ii] = sn;
            out[(size_t)t * N_NEUR + ii] = sn;
        }
        __syncthreads();
        if (tid == 0) cnt = 0;
        __syncthreads();
    }
}

// ---------------------------------------------------------------------------
// Fallback path (round-3 proven) if ws is too small for seg arrays.
// ---------------------------------------------------------------------------
#define NSCAN 64
#define CH 64
#define NCH (T_STEPS / CH)

__global__ __launch_bounds__(64, 1) void k_scan_fb(const float* __restrict__ x,
                                                   const float* __restrict__ u0,
                                                   const float* __restrict__ s0,
                                                   float* __restrict__ out,
                                                   int* __restrict__ flags) {
    const int b = (int)blockIdx.x;
    const int tid = (int)threadIdx.x;
    if (b >= NSCAN) {
        const int t = b - NSCAN;
        const float scale = powf(DECAY, (float)(t + 1));
        const float4* s4 = (const float4*)s0;
        float4* o4 = (float4*)out + (size_t)t * NF4;
        #pragma unroll
        for (int p = 0; p < 16; ++p) {
            const int c = p * 64 + tid;
            float4 v = s4[c];
            v.x *= scale; v.y *= scale; v.z *= scale; v.w *= scale;
            o4[c] = v;
        }
        return;
    }
    const int i = b * 64 + tid;
    const float* xp = x + i;
    float uu = u0[i], ss = s0[i], um = uu;
    float A[CH], B[CH], C[CH];
    auto loadch = [&](float (&dst)[CH], int ck) {
        const float* p = xp + (size_t)ck * CH * N_NEUR;
        #pragma unroll
        for (int k = 0; k < CH; ++k) dst[k] = p[(size_t)k * N_NEUR];
    };
    auto compch = [&](const float (&src)[CH]) {
        #pragma unroll
        for (int k = 0; k < CH; ++k) {
            um = fmaxf(um, uu);
            uu = fmaf(DT, fmaf(uu, uu, src[k] + ss), uu);
            ss *= DECAY;
        }
    };
    loadch(A, 0); loadch(B, 1);
    #pragma unroll 1
    for (int c = 0; c < NCH - 2; c += 3) {
        loadch(C, c + 2); compch(A);
        loadch(A, c + 3); compch(B);
        loadch(B, c + 4); compch(C);
    }
    compch(A); compch(B);
    const unsigned long long anyb = __ballot(um >= 50.0f);
    if (tid == 0) flags[b] = (anyb != 0ull) ? 1 : 0;
}

__global__ __launch_bounds__(1024) void k_slow_fb(const float* __restrict__ x,
                                                  const float* __restrict__ W,
                                                  const float* __restrict__ u0,
                                                  const float* __restrict__ s0,
                                                  float* __restrict__ out,
                                                  const int* __restrict__ flags) {
    __shared__ int any;
    const int tid = (int)threadIdx.x;
    if (tid == 0) any = 0;
    __syncthreads();
    if (tid < NSCAN && flags[tid] != 0) any = 1;
    __syncthreads();
    if (any == 0) return;
    __shared__ float u[N_NEUR];
    __shared__ float s[N_NEUR];
    __shared__ int list[N_NEUR];
    __shared__ int cnt;
    for (int m = tid; m < N_NEUR; m += 1024) { u[m] = u0[m]; s[m] = s0[m]; }
    if (tid == 0) cnt = 0;
    __syncthreads();
    for (int t = 0; t < T_STEPS; ++t) {
        #pragma unroll
        for (int q = 0; q < 4; ++q) {
            const int i = tid + q * 1024;
            const float ui = u[i];
            const bool spk = ui >= V_TH;
            float un = ui + DT * (ui * ui + x[(size_t)t * N_NEUR + i] + s[i]);
            if (spk) { int p = atomicAdd(&cnt, 1); list[p] = i; un = V_R; }
            u[i] = un;
        }
        __syncthreads();
        const int k = cnt;
        #pragma unroll
        for (int q = 0; q < 4; ++q) {
            const int i = tid + q * 1024;
            float acc = 0.f;
            for (int m = 0; m < k; ++m) acc += W[(size_t)i * N_NEUR + list[m]];
            const float sn = s[i] * DECAY + acc;
            s[i] = sn;
            out[(size_t)t * N_NEUR + i] = sn;
        }
        __syncthreads();
        if (tid == 0) cnt = 0;
        __syncthreads();
    }
}

// ---------------------------------------------------------------------------
extern "C" void kernel_launch(void* const* d_in, const int* in_sizes, int n_in,
                              void* d_out, int out_size, void* d_ws, size_t ws_size,
                              hipStream_t stream) {
    const float* x  = (const float*)d_in[0];   // [T, N]
    const float* W  = (const float*)d_in[1];   // [N, N]
    const float* u0 = (const float*)d_in[2];   // [N]
    const float* s0 = (const float*)d_in[3];   // [N]
    float* out = (float*)d_out;                // [T, N]

    const size_t seg_elems = (size_t)NSEG * N_NEUR * 2;    // 1M floats (4 MB)
    if (ws_size >= seg_elems * sizeof(float) + 2 * sizeof(int)) {
        float* seg = (float*)d_ws;
        int* ctl   = (int*)(seg + seg_elems);              // [0]=arrive, [1]=verdict
        k_main<<<PRE_B, 256, 0, stream>>>(x, s0, out, seg, ctl);
        k_finish<<<32, 128, 0, stream>>>(x, W, u0, s0, seg, out, ctl);
    } else {
        int* flags = (int*)d_ws;
        k_scan_fb<<<NSCAN + T_STEPS, 64, 0, stream>>>(x, u0, s0, out, flags);
        k_slow_fb<<<1, 1024, 0, stream>>>(x, W, u0, s0, out, flags);
    }
}

// Round 15
// 23.562 us; speedup vs baseline: 1.5421x; 1.0646x over previous
//
#include <hip/hip_runtime.h>

#define N_NEUR 4096
#define T_STEPS 2048
#define DT 0.001f
#define TAU 10.0f
#define V_TH 100.0f
#define V_R -100.0f
#define DECAY (1.0f - DT / TAU)   // 0.9999f

#define SEG 16                    // time steps per prefix sub-segment
#define NSEG (T_STEPS / SEG)      // 128 sub-segments
#define BETA (DT * (float)SEG)    // 0.016 — per-segment bootstrap constant
#define NF4 (N_NEUR / 4)          // 1024 float4 columns
#define STRIPE 16                 // 16 stripes of 64 float4 cols
#define PRE_B (NSEG * STRIPE)     // 2048 blocks

typedef float f4 __attribute__((ext_vector_type(4)));

// ---------------------------------------------------------------------------
// Spike-impossibility proof (segment-wise bootstrap, per neuron):
// While no spike has occurred anywhere, exactly:
//   u_t = u0 + DT*S_t + DT*sum_{j<t} u_j^2 + (decay-sum of s0, |.| <= TAU|s0|)
// Per sub-segment g (16 steps), with base = S at segment start and P_g =
// max in-segment |S_t - base|:  K_g = |u0| + TAU|s0| + eps + DT*(|base|+P_g) + c_g,
// M_g = 1.5*K_g. If (checked in fp) M_g >= K_g + BETA*M_g^2 then |u_t| <= M_g
// throughout segment g by induction; c_{g+1} = c_g + BETA*M_g^2. If also
// M_g < 50 (half of v_th, ~100x above actual dynamics) for all g,i -> no spike
// can ever fire -> s is pure decay -> out[t] = s0*DECAY^(t+1).
// Any failed / NaN check falls to the exact sequential simulator.
//
// R15 A/B: identical to R14 except ALL nontemporal hints removed — testing
// whether NT was defeating Infinity-Cache retention across timed replays.
// ---------------------------------------------------------------------------

// K1 (2048 blocks x 256, 32 waves/CU): fused out-writer + x-prefix-stats.
__global__ __launch_bounds__(256, 8) void k_main(const float* __restrict__ x,
                                                 const float* __restrict__ s0,
                                                 float* __restrict__ out,
                                                 float* __restrict__ seg,
                                                 int* __restrict__ ctl) {
    const int b = (int)blockIdx.x;
    const int tid = (int)threadIdx.x;
    if (b == 0 && tid == 0) { ctl[0] = 0; ctl[1] = 0; }   // arrive-counter, verdict

    const int ss = b >> 4;
    const int st = b & 15;
    const int c  = tid & 63;
    const int q  = tid >> 6;
    const int f4c = st * 64 + c;
    const int row0 = ss * SEG + q * 4;

    // s0 (L2/L3-cached after first touch)
    const f4 sv = ((const f4*)s0)[f4c];

    // 4 x-loads (cached — L3 can retain x across timed replays)
    const f4* xp = (const f4*)x + (size_t)row0 * NF4 + f4c;
    f4 L[4];
    #pragma unroll
    for (int k = 0; k < 4; ++k) L[k] = xp[(size_t)k * NF4];

    // out rows row0..row0+3 (need only sv -> issue under x-load latency)
    float scale = powf(DECAY, (float)(row0 + 1));
    f4* op = (f4*)out + (size_t)row0 * NF4 + f4c;
    #pragma unroll
    for (int k = 0; k < 4; ++k) {
        op[(size_t)k * NF4] = sv * scale;
        scale *= DECAY;
    }

    // partial prefix over 4 rows
    f4 run = {0.f, 0.f, 0.f, 0.f};
    f4 mx  = {0.f, 0.f, 0.f, 0.f};
    f4 mn  = {0.f, 0.f, 0.f, 0.f};
    #pragma unroll
    for (int k = 0; k < 4; ++k) {
        run.x += L[k].x; mx.x = fmaxf(mx.x, run.x); mn.x = fminf(mn.x, run.x);
        run.y += L[k].y; mx.y = fmaxf(mx.y, run.y); mn.y = fminf(mn.y, run.y);
        run.z += L[k].z; mx.z = fmaxf(mx.z, run.z); mn.z = fminf(mn.z, run.z);
        run.w += L[k].w; mx.w = fmaxf(mx.w, run.w); mn.w = fminf(mn.w, run.w);
    }

    // combine quarters in LDS (12 KB/block; 8 blocks/CU = 96 KB < 160)
    __shared__ f4 Lsum[4][64];
    __shared__ f4 Lmx[4][64];
    __shared__ f4 Lmn[4][64];
    Lsum[q][c] = run;
    Lmx[q][c]  = mx;
    Lmn[q][c]  = mn;
    __syncthreads();

    if (q == 0) {
        float bx = 0.f, by = 0.f, bz = 0.f, bw = 0.f;
        float Mx = 0.f, My = 0.f, Mz = 0.f, Mw = 0.f;
        float Nx = 0.f, Ny = 0.f, Nz = 0.f, Nw = 0.f;
        #pragma unroll
        for (int qq = 0; qq < 4; ++qq) {
            const f4 sS = Lsum[qq][c];
            const f4 sM = Lmx[qq][c];
            const f4 sN = Lmn[qq][c];
            Mx = fmaxf(Mx, bx + sM.x); Nx = fminf(Nx, bx + sN.x); bx += sS.x;
            My = fmaxf(My, by + sM.y); Ny = fminf(Ny, by + sN.y); by += sS.y;
            Mz = fmaxf(Mz, bz + sM.z); Nz = fminf(Nz, bz + sN.z); bz += sS.z;
            Mw = fmaxf(Mw, bw + sM.w); Nw = fminf(Nw, bw + sN.w); bw += sS.w;
        }
        // packed per-neuron float2 {sum, P}: seg2[g*N + i]
        const f4 a  = {bx, fmaxf(Mx, -Nx), by, fmaxf(My, -Ny)};
        const f4 cc = {bz, fmaxf(Mz, -Nz), bw, fmaxf(Mw, -Nw)};
        f4* sp = (f4*)seg + (size_t)ss * (N_NEUR / 2) + (size_t)f4c * 2;
        sp[0] = a;
        sp[1] = cc;
    }
}

// K2 (32 blocks x 128): bootstrap combine + last-arriving-block exact-sim
// fallback (R13, proven).
#define CSEG 32
__global__ __launch_bounds__(128) void k_finish(const float* __restrict__ x,
                                                const float* __restrict__ W,
                                                const float* __restrict__ u0,
                                                const float* __restrict__ s0,
                                                const float* __restrict__ seg,
                                                float* __restrict__ out,
                                                int* __restrict__ ctl) {
    const int tid = (int)threadIdx.x;
    const int i = (int)blockIdx.x * 128 + tid;

    const float base_term = fabsf(u0[i]) + TAU * fabsf(s0[i]) + 1e-3f;
    const float2* seg2 = (const float2*)seg;

    bool bad = false;
    float base = 0.f;
    float cq = 0.f;
    #pragma unroll 1
    for (int c0 = 0; c0 < NSEG; c0 += CSEG) {
        float2 SP[CSEG];
        #pragma unroll
        for (int k = 0; k < CSEG; ++k)
            SP[k] = seg2[(size_t)(c0 + k) * N_NEUR + i];
        #pragma unroll
        for (int k = 0; k < CSEG; ++k) {
            const float K = base_term + DT * (fabsf(base) + SP[k].y) + cq;
            const float M = 1.5f * K;
            bad |= !(M >= K + BETA * M * M);       // bootstrap check (NaN-safe)
            bad |= !(M < 50.0f);                   // spike margin check
            cq += BETA * M * M;
            base += SP[k].x;
        }
    }

    __shared__ int blkbad;
    __shared__ int lastflag;
    __shared__ int globad;
    if (tid == 0) { blkbad = 0; lastflag = 0; globad = 0; }
    __syncthreads();
    if (bad) atomicOr(&blkbad, 1);
    __syncthreads();
    if (tid == 0) {
        if (blkbad) atomicOr(&ctl[1], 1);          // device-scope verdict OR
        __threadfence();                           // release before arrive
        const int old = atomicAdd(&ctl[0], 1);     // arrive
        if (old == 31) {                           // last of 32 blocks
            lastflag = 1;
            __threadfence();                       // acquire
            globad = atomicOr(&ctl[1], 0);         // coherent read
        }
    }
    __syncthreads();
    if (!lastflag || globad == 0) return;          // expected path: fast exit

    // exact sequential fallback (last block only; never for in-dist data)
    __shared__ float u[N_NEUR];
    __shared__ float s[N_NEUR];
    __shared__ int list[N_NEUR];
    __shared__ int cnt;
    for (int m = tid; m < N_NEUR; m += 128) { u[m] = u0[m]; s[m] = s0[m]; }
    if (tid == 0) cnt = 0;
    __syncthreads();
    for (int t = 0; t < T_STEPS; ++t) {
        #pragma unroll
        for (int qq = 0; qq < 32; ++qq) {
            const int ii = tid + qq * 128;
            const float ui = u[ii];
            const bool spk = ui >= V_TH;
            float un = ui + DT * (ui * ui + x[(size_t)t * N_NEUR + ii] + s[ii]);
            if (spk) {
                int p = atomicAdd(&cnt, 1);
                list[p] = ii;
                un = V_R;
            }
            u[ii] = un;
        }
        __syncthreads();
        const int k = cnt;
        #pragma unroll
        for (int qq = 0; qq < 32; ++qq) {
            const int ii = tid + qq * 128;
            float acc = 0.f;
            for (int m = 0; m < k; ++m) acc += W[(size_t)ii * N_NEUR + list[m]];
            const float sn = s[ii] * DECAY + acc;
            s[ii] = sn;
            out[(size_t)t * N_NEUR + ii] = sn;
        }
        __syncthreads();
        if (tid == 0) cnt = 0;
        __syncthreads();
    }
}

// ---------------------------------------------------------------------------
// Fallback path (round-3 proven) if ws is too small for seg arrays.
// ---------------------------------------------------------------------------
#define NSCAN 64
#define CH 64
#define NCH (T_STEPS / CH)

__global__ __launch_bounds__(64, 1) void k_scan_fb(const float* __restrict__ x,
                                                   const float* __restrict__ u0,
                                                   const float* __restrict__ s0,
                                                   float* __restrict__ out,
                                                   int* __restrict__ flags) {
    const int b = (int)blockIdx.x;
    const int tid = (int)threadIdx.x;
    if (b >= NSCAN) {
        const int t = b - NSCAN;
        const float scale = powf(DECAY, (float)(t + 1));
        const float4* s4 = (const float4*)s0;
        float4* o4 = (float4*)out + (size_t)t * NF4;
        #pragma unroll
        for (int p = 0; p < 16; ++p) {
            const int c = p * 64 + tid;
            float4 v = s4[c];
            v.x *= scale; v.y *= scale; v.z *= scale; v.w *= scale;
            o4[c] = v;
        }
        return;
    }
    const int i = b * 64 + tid;
    const float* xp = x + i;
    float uu = u0[i], ss = s0[i], um = uu;
    float A[CH], B[CH], C[CH];
    auto loadch = [&](float (&dst)[CH], int ck) {
        const float* p = xp + (size_t)ck * CH * N_NEUR;
        #pragma unroll
        for (int k = 0; k < CH; ++k) dst[k] = p[(size_t)k * N_NEUR];
    };
    auto compch = [&](const float (&src)[CH]) {
        #pragma unroll
        for (int k = 0; k < CH; ++k) {
            um = fmaxf(um, uu);
            uu = fmaf(DT, fmaf(uu, uu, src[k] + ss), uu);
            ss *= DECAY;
        }
    };
    loadch(A, 0); loadch(B, 1);
    #pragma unroll 1
    for (int c = 0; c < NCH - 2; c += 3) {
        loadch(C, c + 2); compch(A);
        loadch(A, c + 3); compch(B);
        loadch(B, c + 4); compch(C);
    }
    compch(A); compch(B);
    const unsigned long long anyb = __ballot(um >= 50.0f);
    if (tid == 0) flags[b] = (anyb != 0ull) ? 1 : 0;
}

__global__ __launch_bounds__(1024) void k_slow_fb(const float* __restrict__ x,
                                                  const float* __restrict__ W,
                                                  const float* __restrict__ u0,
                                                  const float* __restrict__ s0,
                                                  float* __restrict__ out,
                                                  const int* __restrict__ flags) {
    __shared__ int any;
    const int tid = (int)threadIdx.x;
    if (tid == 0) any = 0;
    __syncthreads();
    if (tid < NSCAN && flags[tid] != 0) any = 1;
    __syncthreads();
    if (any == 0) return;
    __shared__ float u[N_NEUR];
    __shared__ float s[N_NEUR];
    __shared__ int list[N_NEUR];
    __shared__ int cnt;
    for (int m = tid; m < N_NEUR; m += 1024) { u[m] = u0[m]; s[m] = s0[m]; }
    if (tid == 0) cnt = 0;
    __syncthreads();
    for (int t = 0; t < T_STEPS; ++t) {
        #pragma unroll
        for (int q = 0; q < 4; ++q) {
            const int i = tid + q * 1024;
            const float ui = u[i];
            const bool spk = ui >= V_TH;
            float un = ui + DT * (ui * ui + x[(size_t)t * N_NEUR + i] + s[i]);
            if (spk) { int p = atomicAdd(&cnt, 1); list[p] = i; un = V_R; }
            u[i] = un;
        }
        __syncthreads();
        const int k = cnt;
        #pragma unroll
        for (int q = 0; q < 4; ++q) {
            const int i = tid + q * 1024;
            float acc = 0.f;
            for (int m = 0; m < k; ++m) acc += W[(size_t)i * N_NEUR + list[m]];
            const float sn = s[i] * DECAY + acc;
            s[i] = sn;
            out[(size_t)t * N_NEUR + i] = sn;
        }
        __syncthreads();
        if (tid == 0) cnt = 0;
        __syncthreads();
    }
}

// ---------------------------------------------------------------------------
extern "C" void kernel_launch(void* const* d_in, const int* in_sizes, int n_in,
                              void* d_out, int out_size, void* d_ws, size_t ws_size,
                              hipStream_t stream) {
    const float* x  = (const float*)d_in[0];   // [T, N]
    const float* W  = (const float*)d_in[1];   // [N, N]
    const float* u0 = (const float*)d_in[2];   // [N]
    const float* s0 = (const float*)d_in[3];   // [N]
    float* out = (float*)d_out;                // [T, N]

    const size_t seg_elems = (size_t)NSEG * N_NEUR * 2;    // 1M floats (4 MB)
    if (ws_size >= seg_elems * sizeof(float) + 2 * sizeof(int)) {
        float* seg = (float*)d_ws;
        int* ctl   = (int*)(seg + seg_elems);              // [0]=arrive, [1]=verdict
        k_main<<<PRE_B, 256, 0, stream>>>(x, s0, out, seg, ctl);
        k_finish<<<32, 128, 0, stream>>>(x, W, u0, s0, seg, out, ctl);
    } else {
        int* flags = (int*)d_ws;
        k_scan_fb<<<NSCAN + T_STEPS, 64, 0, stream>>>(x, u0, s0, out, flags);
        k_slow_fb<<<1, 1024, 0, stream>>>(x, W, u0, s0, out, flags);
    }
}

// Round 16
// 23.159 us; speedup vs baseline: 1.5690x; 1.0174x over previous
//
#include <hip/hip_runtime.h>

#define N_NEUR 4096
#define T_STEPS 2048
#define DT 0.001f
#define TAU 10.0f
#define V_TH 100.0f
#define V_R -100.0f
#define DECAY (1.0f - DT / TAU)   // 0.9999f

#define SEG 16                    // time steps per prefix sub-segment
#define NSEG (T_STEPS / SEG)      // 128 sub-segments
#define BETA (DT * (float)SEG)    // 0.016 — per-segment bootstrap constant
#define NF4 (N_NEUR / 4)          // 1024 float4 columns
#define STRIPE 16                 // 16 stripes of 64 float4 cols
#define PRE_B (NSEG * STRIPE)     // 2048 blocks

typedef float f4 __attribute__((ext_vector_type(4)));

// ---------------------------------------------------------------------------
// Spike-impossibility proof (segment-wise bootstrap, per neuron):
// While no spike has occurred anywhere, exactly:
//   u_t = u0 + DT*S_t + DT*sum_{j<t} u_j^2 + (decay-sum of s0, |.| <= TAU|s0|)
// Per sub-segment g (16 steps), with base = S at segment start and P_g =
// max in-segment |S_t - base|:  K_g = |u0| + TAU|s0| + eps + DT*(|base|+P_g) + c_g,
// M_g = 1.5*K_g. If (checked in fp) M_g >= K_g + BETA*M_g^2 then |u_t| <= M_g
// throughout segment g by induction; c_{g+1} = c_g + BETA*M_g^2. If also
// M_g < 50 (half of v_th, ~100x above actual dynamics) for all g,i -> no spike
// can ever fire -> s is pure decay -> out[t] = s0*DECAY^(t+1).
// Any failed / NaN check falls to the exact sequential simulator.
//
// R16 A/B vs R15: ONLY change is __launch_bounds__(256,8) -> (256,4).
// 8 waves/EU capped VGPRs at 32 -> the 4-deep f4 load buffer couldn't
// materialize (R1 failure mode); 4 waves/EU gives 64 VGPR + 2 residency
// rounds of block turnover.
// ---------------------------------------------------------------------------

// K1 (2048 blocks x 256, 4 blocks/CU resident, 2 rounds):
// fused out-writer + x-prefix-stats.
__global__ __launch_bounds__(256, 4) void k_main(const float* __restrict__ x,
                                                 const float* __restrict__ s0,
                                                 float* __restrict__ out,
                                                 float* __restrict__ seg,
                                                 int* __restrict__ ctl) {
    const int b = (int)blockIdx.x;
    const int tid = (int)threadIdx.x;
    if (b == 0 && tid == 0) { ctl[0] = 0; ctl[1] = 0; }   // arrive-counter, verdict

    const int ss = b >> 4;
    const int st = b & 15;
    const int c  = tid & 63;
    const int q  = tid >> 6;
    const int f4c = st * 64 + c;
    const int row0 = ss * SEG + q * 4;

    // s0 (L2/L3-cached after first touch)
    const f4 sv = ((const f4*)s0)[f4c];

    // 4 x-loads, breadth-first (now have the VGPR budget to keep in flight)
    const f4* xp = (const f4*)x + (size_t)row0 * NF4 + f4c;
    f4 L[4];
    #pragma unroll
    for (int k = 0; k < 4; ++k) L[k] = xp[(size_t)k * NF4];

    // out rows row0..row0+3 (need only sv -> issue under x-load latency)
    float scale = powf(DECAY, (float)(row0 + 1));
    f4* op = (f4*)out + (size_t)row0 * NF4 + f4c;
    #pragma unroll
    for (int k = 0; k < 4; ++k) {
        op[(size_t)k * NF4] = sv * scale;
        scale *= DECAY;
    }

    // partial prefix over 4 rows
    f4 run = {0.f, 0.f, 0.f, 0.f};
    f4 mx  = {0.f, 0.f, 0.f, 0.f};
    f4 mn  = {0.f, 0.f, 0.f, 0.f};
    #pragma unroll
    for (int k = 0; k < 4; ++k) {
        run.x += L[k].x; mx.x = fmaxf(mx.x, run.x); mn.x = fminf(mn.x, run.x);
        run.y += L[k].y; mx.y = fmaxf(mx.y, run.y); mn.y = fminf(mn.y, run.y);
        run.z += L[k].z; mx.z = fmaxf(mx.z, run.z); mn.z = fminf(mn.z, run.z);
        run.w += L[k].w; mx.w = fmaxf(mx.w, run.w); mn.w = fminf(mn.w, run.w);
    }

    // combine quarters in LDS (12 KB/block; 4 blocks/CU = 48 KB < 160)
    __shared__ f4 Lsum[4][64];
    __shared__ f4 Lmx[4][64];
    __shared__ f4 Lmn[4][64];
    Lsum[q][c] = run;
    Lmx[q][c]  = mx;
    Lmn[q][c]  = mn;
    __syncthreads();

    if (q == 0) {
        float bx = 0.f, by = 0.f, bz = 0.f, bw = 0.f;
        float Mx = 0.f, My = 0.f, Mz = 0.f, Mw = 0.f;
        float Nx = 0.f, Ny = 0.f, Nz = 0.f, Nw = 0.f;
        #pragma unroll
        for (int qq = 0; qq < 4; ++qq) {
            const f4 sS = Lsum[qq][c];
            const f4 sM = Lmx[qq][c];
            const f4 sN = Lmn[qq][c];
            Mx = fmaxf(Mx, bx + sM.x); Nx = fminf(Nx, bx + sN.x); bx += sS.x;
            My = fmaxf(My, by + sM.y); Ny = fminf(Ny, by + sN.y); by += sS.y;
            Mz = fmaxf(Mz, bz + sM.z); Nz = fminf(Nz, bz + sN.z); bz += sS.z;
            Mw = fmaxf(Mw, bw + sM.w); Nw = fminf(Nw, bw + sN.w); bw += sS.w;
        }
        // packed per-neuron float2 {sum, P}: seg2[g*N + i]
        const f4 a  = {bx, fmaxf(Mx, -Nx), by, fmaxf(My, -Ny)};
        const f4 cc = {bz, fmaxf(Mz, -Nz), bw, fmaxf(Mw, -Nw)};
        f4* sp = (f4*)seg + (size_t)ss * (N_NEUR / 2) + (size_t)f4c * 2;
        sp[0] = a;
        sp[1] = cc;
    }
}

// K2 (32 blocks x 128): bootstrap combine + last-arriving-block exact-sim
// fallback (R13, proven).
#define CSEG 32
__global__ __launch_bounds__(128) void k_finish(const float* __restrict__ x,
                                                const float* __restrict__ W,
                                                const float* __restrict__ u0,
                                                const float* __restrict__ s0,
                                                const float* __restrict__ seg,
                                                float* __restrict__ out,
                                                int* __restrict__ ctl) {
    const int tid = (int)threadIdx.x;
    const int i = (int)blockIdx.x * 128 + tid;

    const float base_term = fabsf(u0[i]) + TAU * fabsf(s0[i]) + 1e-3f;
    const float2* seg2 = (const float2*)seg;

    bool bad = false;
    float base = 0.f;
    float cq = 0.f;
    #pragma unroll 1
    for (int c0 = 0; c0 < NSEG; c0 += CSEG) {
        float2 SP[CSEG];
        #pragma unroll
        for (int k = 0; k < CSEG; ++k)
            SP[k] = seg2[(size_t)(c0 + k) * N_NEUR + i];
        #pragma unroll
        for (int k = 0; k < CSEG; ++k) {
            const float K = base_term + DT * (fabsf(base) + SP[k].y) + cq;
            const float M = 1.5f * K;
            bad |= !(M >= K + BETA * M * M);       // bootstrap check (NaN-safe)
            bad |= !(M < 50.0f);                   // spike margin check
            cq += BETA * M * M;
            base += SP[k].x;
        }
    }

    __shared__ int blkbad;
    __shared__ int lastflag;
    __shared__ int globad;
    if (tid == 0) { blkbad = 0; lastflag = 0; globad = 0; }
    __syncthreads();
    if (bad) atomicOr(&blkbad, 1);
    __syncthreads();
    if (tid == 0) {
        if (blkbad) atomicOr(&ctl[1], 1);          // device-scope verdict OR
        __threadfence();                           // release before arrive
        const int old = atomicAdd(&ctl[0], 1);     // arrive
        if (old == 31) {                           // last of 32 blocks
            lastflag = 1;
            __threadfence();                       // acquire
            globad = atomicOr(&ctl[1], 0);         // coherent read
        }
    }
    __syncthreads();
    if (!lastflag || globad == 0) return;          // expected path: fast exit

    // exact sequential fallback (last block only; never for in-dist data)
    __shared__ float u[N_NEUR];
    __shared__ float s[N_NEUR];
    __shared__ int list[N_NEUR];
    __shared__ int cnt;
    for (int m = tid; m < N_NEUR; m += 128) { u[m] = u0[m]; s[m] = s0[m]; }
    if (tid == 0) cnt = 0;
    __syncthreads();
    for (int t = 0; t < T_STEPS; ++t) {
        #pragma unroll
        for (int qq = 0; qq < 32; ++qq) {
            const int ii = tid + qq * 128;
            const float ui = u[ii];
            const bool spk = ui >= V_TH;
            float un = ui + DT * (ui * ui + x[(size_t)t * N_NEUR + ii] + s[ii]);
            if (spk) {
                int p = atomicAdd(&cnt, 1);
                list[p] = ii;
                un = V_R;
            }
            u[ii] = un;
        }
        __syncthreads();
        const int k = cnt;
        #pragma unroll
        for (int qq = 0; qq < 32; ++qq) {
            const int ii = tid + qq * 128;
            float acc = 0.f;
            for (int m = 0; m < k; ++m) acc += W[(size_t)ii * N_NEUR + list[m]];
            const float sn = s[ii] * DECAY + acc;
            s[ii] = sn;
            out[(size_t)t * N_NEUR + ii] = sn;
        }
        __syncthreads();
        if (tid == 0) cnt = 0;
        __syncthreads();
    }
}

// ---------------------------------------------------------------------------
// Fallback path (round-3 proven) if ws is too small for seg arrays.
// ---------------------------------------------------------------------------
#define NSCAN 64
#define CH 64
#define NCH (T_STEPS / CH)

__global__ __launch_bounds__(64, 1) void k_scan_fb(const float* __restrict__ x,
                                                   const float* __restrict__ u0,
                                                   const float* __restrict__ s0,
                                                   float* __restrict__ out,
                                                   int* __restrict__ flags) {
    const int b = (int)blockIdx.x;
    const int tid = (int)threadIdx.x;
    if (b >= NSCAN) {
        const int t = b - NSCAN;
        const float scale = powf(DECAY, (float)(t + 1));
        const float4* s4 = (const float4*)s0;
        float4* o4 = (float4*)out + (size_t)t * NF4;
        #pragma unroll
        for (int p = 0; p < 16; ++p) {
            const int c = p * 64 + tid;
            float4 v = s4[c];
            v.x *= scale; v.y *= scale; v.z *= scale; v.w *= scale;
            o4[c] = v;
        }
        return;
    }
    const int i = b * 64 + tid;
    const float* xp = x + i;
    float uu = u0[i], ss = s0[i], um = uu;
    float A[CH], B[CH], C[CH];
    auto loadch = [&](float (&dst)[CH], int ck) {
        const float* p = xp + (size_t)ck * CH * N_NEUR;
        #pragma unroll
        for (int k = 0; k < CH; ++k) dst[k] = p[(size_t)k * N_NEUR];
    };
    auto compch = [&](const float (&src)[CH]) {
        #pragma unroll
        for (int k = 0; k < CH; ++k) {
            um = fmaxf(um, uu);
            uu = fmaf(DT, fmaf(uu, uu, src[k] + ss), uu);
            ss *= DECAY;
        }
    };
    loadch(A, 0); loadch(B, 1);
    #pragma unroll 1
    for (int c = 0; c < NCH - 2; c += 3) {
        loadch(C, c + 2); compch(A);
        loadch(A, c + 3); compch(B);
        loadch(B, c + 4); compch(C);
    }
    compch(A); compch(B);
    const unsigned long long anyb = __ballot(um >= 50.0f);
    if (tid == 0) flags[b] = (anyb != 0ull) ? 1 : 0;
}

__global__ __launch_bounds__(1024) void k_slow_fb(const float* __restrict__ x,
                                                  const float* __restrict__ W,
                                                  const float* __restrict__ u0,
                                                  const float* __restrict__ s0,
                                                  float* __restrict__ out,
                                                  const int* __restrict__ flags) {
    __shared__ int any;
    const int tid = (int)threadIdx.x;
    if (tid == 0) any = 0;
    __syncthreads();
    if (tid < NSCAN && flags[tid] != 0) any = 1;
    __syncthreads();
    if (any == 0) return;
    __shared__ float u[N_NEUR];
    __shared__ float s[N_NEUR];
    __shared__ int list[N_NEUR];
    __shared__ int cnt;
    for (int m = tid; m < N_NEUR; m += 1024) { u[m] = u0[m]; s[m] = s0[m]; }
    if (tid == 0) cnt = 0;
    __syncthreads();
    for (int t = 0; t < T_STEPS; ++t) {
        #pragma unroll
        for (int q = 0; q < 4; ++q) {
            const int i = tid + q * 1024;
            const float ui = u[i];
            const bool spk = ui >= V_TH;
            float un = ui + DT * (ui * ui + x[(size_t)t * N_NEUR + i] + s[i]);
            if (spk) { int p = atomicAdd(&cnt, 1); list[p] = i; un = V_R; }
            u[i] = un;
        }
        __syncthreads();
        const int k = cnt;
        #pragma unroll
        for (int q = 0; q < 4; ++q) {
            const int i = tid + q * 1024;
            float acc = 0.f;
            for (int m = 0; m < k; ++m) acc += W[(size_t)i * N_NEUR + list[m]];
            const float sn = s[i] * DECAY + acc;
            s[i] = sn;
            out[(size_t)t * N_NEUR + i] = sn;
        }
        __syncthreads();
        if (tid == 0) cnt = 0;
        __syncthreads();
    }
}

// ---------------------------------------------------------------------------
extern "C" void kernel_launch(void* const* d_in, const int* in_sizes, int n_in,
                              void* d_out, int out_size, void* d_ws, size_t ws_size,
                              hipStream_t stream) {
    const float* x  = (const float*)d_in[0];   // [T, N]
    const float* W  = (const float*)d_in[1];   // [N, N]
    const float* u0 = (const float*)d_in[2];   // [N]
    const float* s0 = (const float*)d_in[3];   // [N]
    float* out = (float*)d_out;                // [T, N]

    const size_t seg_elems = (size_t)NSEG * N_NEUR * 2;    // 1M floats (4 MB)
    if (ws_size >= seg_elems * sizeof(float) + 2 * sizeof(int)) {
        float* seg = (float*)d_ws;
        int* ctl   = (int*)(seg + seg_elems);              // [0]=arrive, [1]=verdict
        k_main<<<PRE_B, 256, 0, stream>>>(x, s0, out, seg, ctl);
        k_finish<<<32, 128, 0, stream>>>(x, W, u0, s0, seg, out, ctl);
    } else {
        int* flags = (int*)d_ws;
        k_scan_fb<<<NSCAN + T_STEPS, 64, 0, stream>>>(x, u0, s0, out, flags);
        k_slow_fb<<<1, 1024, 0, stream>>>(x, W, u0, s0, out, flags);
    }
}